// Round 1
// baseline (86.898 us; speedup 1.0000x reference)
//
#include <hip/hip_runtime.h>
#include <math.h>

// Problem constants (fixed by reference setup_inputs):
// support: (B, N, K, D) fp32, query: (B, Q, D) fp32
// out = concat(agg (B,N,D), qgw (B,N,K,1)) fp32
constexpr int B = 4;
constexpr int N = 10;
constexpr int K = 5;
constexpr int Q = 512;
constexpr int D = 1536;  // 2 * 768

// Workspace layout (floats):
// [0, B*D)        : qbar sums  (sum over q of query[b,q,d])
// [B*D, B*D+B)    : csum       (sum over q of ||query[b,q]||^2)
constexpr int QBAR_OFF = 0;
constexpr int CSUM_OFF = B * D;

// Kernel 1: per-b query column sums + sum of squares.
// grid = (Q/64, D/256, B), block = 256. Thread handles one d, 64 queries.
__global__ __launch_bounds__(256) void qstats_kernel(
    const float* __restrict__ query, float* __restrict__ ws) {
    const int tid = threadIdx.x;
    const int d   = blockIdx.y * 256 + tid;
    const int b   = blockIdx.z;
    const int q0  = blockIdx.x * 64;

    const float* qp = query + (size_t)b * Q * D + (size_t)q0 * D + d;
    float acc = 0.f, ssq = 0.f;
#pragma unroll 8
    for (int q = 0; q < 64; ++q) {
        float v = qp[(size_t)q * D];
        acc += v;
        ssq = fmaf(v, v, ssq);
    }
    atomicAdd(&ws[QBAR_OFF + b * D + d], acc);

    // block-reduce ssq: wave64 shuffle then cross-wave via LDS
    for (int off = 32; off > 0; off >>= 1) ssq += __shfl_down(ssq, off);
    __shared__ float red[4];
    const int wave = tid >> 6, lane = tid & 63;
    if (lane == 0) red[wave] = ssq;
    __syncthreads();
    if (tid == 0) {
        atomicAdd(&ws[CSUM_OFF + b], red[0] + red[1] + red[2] + red[3]);
    }
}

// Kernel 2: per (b,n) block — dot products vs qbar, tanh, softmax over K,
// write qgw, then weighted shot-aggregation.
// grid = B*N, block = 256.
__global__ __launch_bounds__(256) void agg_kernel(
    const float* __restrict__ support, const float* __restrict__ ws,
    float* __restrict__ out) {
    const int tid = threadIdx.x;
    const int bn  = blockIdx.x;      // 0..B*N-1
    const int b   = bn / N;

    const float* sup  = support + (size_t)bn * K * D;
    const float* qbar = ws + QBAR_OFF + (size_t)b * D;

    __shared__ float s_red[2][K][4];
    __shared__ float s_w[K];

    const int wave = tid >> 6, lane = tid & 63;

    for (int k = 0; k < K; ++k) {
        float a = 0.f, c = 0.f;
        for (int d = tid; d < D; d += 256) {
            float s = sup[k * D + d];
            a = fmaf(s, s, a);
            c = fmaf(s, qbar[d], c);
        }
        for (int off = 32; off > 0; off >>= 1) {
            a += __shfl_down(a, off);
            c += __shfl_down(c, off);
        }
        if (lane == 0) { s_red[0][k][wave] = a; s_red[1][k][wave] = c; }
    }
    __syncthreads();

    if (tid < K) {
        const int k = tid;
        float ssk = s_red[0][k][0] + s_red[0][k][1] + s_red[0][k][2] + s_red[0][k][3];
        float sqk = s_red[1][k][0] + s_red[1][k][1] + s_red[1][k][2] + s_red[1][k][3];
        float cb  = ws[CSUM_OFF + b] * (1.f / Q);
        // mean_q dist_sq = -||S||^2 + 2*S.qbar_mean - mean||q||^2
        float m = -ssk + 2.f * sqk * (1.f / Q) - cb;
        s_w[k] = tanhf(m);
    }
    __syncthreads();
    if (tid == 0) {
        float mx = s_w[0];
        for (int k = 1; k < K; ++k) mx = fmaxf(mx, s_w[k]);
        float e[K], sum = 0.f;
        for (int k = 0; k < K; ++k) { e[k] = expf(s_w[k] - mx); sum += e[k]; }
        float inv = 1.f / sum;
        for (int k = 0; k < K; ++k) s_w[k] = e[k] * inv;
    }
    __syncthreads();

    // qgw output (after agg block: B*N*D floats)
    if (tid < K) out[(size_t)B * N * D + bn * K + tid] = s_w[tid];

    float w[K];
#pragma unroll
    for (int k = 0; k < K; ++k) w[k] = s_w[k];

    for (int d = tid; d < D; d += 256) {
        float acc = 0.f;
#pragma unroll
        for (int k = 0; k < K; ++k) acc = fmaf(sup[k * D + d], w[k], acc);
        out[(size_t)bn * D + d] = acc;
    }
}

extern "C" void kernel_launch(void* const* d_in, const int* in_sizes, int n_in,
                              void* d_out, int out_size, void* d_ws, size_t ws_size,
                              hipStream_t stream) {
    const float* support = (const float*)d_in[0];
    const float* query   = (const float*)d_in[1];
    float* out = (float*)d_out;
    float* ws  = (float*)d_ws;

    // zero the atomic accumulators (ws is poisoned to 0xAA before each launch)
    hipMemsetAsync(d_ws, 0, (size_t)(B * D + B) * sizeof(float), stream);

    dim3 g1(Q / 64, D / 256, B);   // 8 * 6 * 4 = 192 blocks
    qstats_kernel<<<g1, 256, 0, stream>>>(query, ws);

    agg_kernel<<<B * N, 256, 0, stream>>>(support, ws, out);
}